// Round 1
// baseline (318.960 us; speedup 1.0000x reference)
//
#include <hip/hip_runtime.h>
#include <math.h>

// Problem constants
#define BB   4
#define CIN  64
#define HH   64
#define WW   256
#define CO   128
#define HWSZ (HH*WW)          // 16384
#define NPIX (BB*HH*WW)       // 65536

// Workspace layout (float offsets). Total ~24.2 MB.
#define XT_OFF  0
#define XT_SZ   (BB*HH*WW*CIN)       // 4194304  x transposed to [b][y][x][c]
#define TAP_OFF (XT_OFF + XT_SZ)
#define TAP_SZ  (27*NPIX)            // 1769472  planes: dy[9], dx[9], mask[9]
#define OWT_OFF (TAP_OFF + TAP_SZ)
#define OWT_SZ  (9*CIN*27)           // 15552    offset-weight as [t][c][oc]
#define WT_OFF  (OWT_OFF + OWT_SZ)
#define WT_SZ   (9*CIN*CO)           // 73728    main weight as [k][c][o]

// ---------------------------------------------------------------------------
// K0x: x [B][C][H][W] -> xt [B][H][W][C]  (LDS tile transpose, coalesced both sides)
__global__ __launch_bounds__(256) void k_transpose_x(const float* __restrict__ x,
                                                     float* __restrict__ xt) {
    __shared__ float t[64][65];
    int bx = blockIdx.x;           // 1024 blocks: (b, y, xtile)
    int x0 = (bx & 3) * 64;
    int y  = (bx >> 2) & 63;
    int b  = bx >> 8;
    int tid = threadIdx.x;
    int lx = tid & 63, gy = tid >> 6;
#pragma unroll
    for (int i = 0; i < 16; ++i) {
        int c = i * 4 + gy;
        t[c][lx] = x[((b*CIN + c)*HH + y)*WW + x0 + lx];
    }
    __syncthreads();
#pragma unroll
    for (int i = 0; i < 16; ++i) {
        int xx = i * 4 + gy;
        xt[(((b*HH + y)*WW) + x0 + xx)*CIN + lx] = t[lx][xx];
    }
}

// ---------------------------------------------------------------------------
// K0w: weight reshuffles (tiny, one-off)
//   owt2[(t*64+c)*27+oc] = ow[(oc*64+c)*9+t]
//   wt  [(k*64+c)*128+o] = wm[(o*64+c)*9+k]
__global__ __launch_bounds__(256) void k_prep_w(const float* __restrict__ ow,
                                                const float* __restrict__ wm,
                                                float* __restrict__ owt2,
                                                float* __restrict__ wt) {
    for (int i = blockIdx.x*blockDim.x + threadIdx.x;
         i < OWT_SZ + WT_SZ; i += gridDim.x*blockDim.x) {
        if (i < OWT_SZ) {
            int t = i / (CIN*27);
            int r = i % (CIN*27);
            int c = r / 27, oc = r % 27;
            owt2[i] = ow[(oc*CIN + c)*9 + t];
        } else {
            int j = i - OWT_SZ;
            int k = j / (CIN*CO);
            int r = j % (CIN*CO);
            int c = r / CO, o = r % CO;
            wt[j] = wm[(o*CIN + c)*9 + k];
        }
    }
}

// ---------------------------------------------------------------------------
// K1: offset conv (27ch, 3x3, pad 1) + bias + split/sigmoid -> tap planes.
// One block per (b,ho) row; thread = wo. Weights via wave-uniform (SMEM) loads.
__global__ __launch_bounds__(256) void k_offconv(const float* __restrict__ xt,
                                                 const float* __restrict__ owt2,
                                                 const float* __restrict__ ob,
                                                 float* __restrict__ tap) {
    int bx = blockIdx.x;            // b*HH + ho
    int b = bx >> 6, ho = bx & 63;
    int wo = threadIdx.x;

    float acc[27];
#pragma unroll
    for (int oc = 0; oc < 27; ++oc) acc[oc] = ob[oc];

    for (int t = 0; t < 9; ++t) {   // runtime loop keeps I$ footprint sane
        int di = t / 3, dj = t % 3;
        int y = ho + di - 1;
        if (y < 0 || y >= HH) continue;      // zero padding rows (uniform)
        int xx = wo + dj - 1;
        bool vx = (xx >= 0) && (xx < WW);
        const float4* p = (const float4*)(xt + (((b*HH + y)*WW) + (vx ? xx : 0))*CIN);
        const float* wp = owt2 + t*CIN*27;   // uniform base
#pragma unroll
        for (int cb = 0; cb < 16; ++cb) {
            float4 v = p[cb];
            if (!vx) { v.x = 0.f; v.y = 0.f; v.z = 0.f; v.w = 0.f; }
#pragma unroll
            for (int oc = 0; oc < 27; ++oc) {
                acc[oc] += v.x * wp[(cb*4+0)*27 + oc];
                acc[oc] += v.y * wp[(cb*4+1)*27 + oc];
                acc[oc] += v.z * wp[(cb*4+2)*27 + oc];
                acc[oc] += v.w * wp[(cb*4+3)*27 + oc];
            }
        }
    }

    int gpix = (b*HH + ho)*WW + wo;
#pragma unroll
    for (int k = 0; k < 9; ++k) {
        tap[k*NPIX + gpix]        = acc[2*k];       // dy_k  (om ch 2k)
        tap[(9+k)*NPIX + gpix]    = acc[2*k+1];     // dx_k  (om ch 2k+1)
        float m = acc[18+k];                        // mask logit (om ch 18+k)
        tap[(18+k)*NPIX + gpix]   = 1.0f / (1.0f + expf(-m));
    }
}

// ---------------------------------------------------------------------------
// K2: deformable sampling + einsum.
// Block = 64 px (quarter row) x all 128 oc. 256 threads.
// Phase 1: threads (px = tid&63, 16 channels per grp) compute bilinear samp -> LDS [c][65].
// Phase 2: threads (px, oc-group of 32) accumulate; weights via uniform SMEM loads.
__global__ __launch_bounds__(256) void k_main(const float* __restrict__ xt,
                                              const float* __restrict__ tap,
                                              const float* __restrict__ wt,
                                              float* __restrict__ out) {
    __shared__ float samp[64*65];
    int bx = blockIdx.x;            // 1024 blocks
    int wtile = bx & 3;
    int ho = (bx >> 2) & 63;
    int b  = bx >> 8;
    int tid = threadIdx.x;
    int px = tid & 63;
    int grp = tid >> 6;             // 0..3
    int wo = wtile*64 + px;
    int gpix = (b*HH + ho)*WW + wo;

    int og = __builtin_amdgcn_readfirstlane(grp);   // wave-uniform oc-group

    float acc[32];
#pragma unroll
    for (int o = 0; o < 32; ++o) acc[o] = 0.f;

    for (int k = 0; k < 9; ++k) {
        // ---- phase 1: bilinear sampling of 16 channels for this thread's pixel
        float dy = tap[k*NPIX + gpix];
        float dx = tap[(9+k)*NPIX + gpix];
        float m  = tap[(18+k)*NPIX + gpix];
        float py  = dy + (float)(ho - 1 + k/3);
        float pxf = dx + (float)(wo - 1 + k%3);
        float y0f = floorf(py), x0f = floorf(pxf);
        float ly = py - y0f, lx = pxf - x0f;
        int y0 = (int)y0f, xi0 = (int)x0f;
        int y1 = y0 + 1,  xi1 = xi0 + 1;
        bool vy0 = (y0 >= 0) && (y0 < HH), vy1 = (y1 >= 0) && (y1 < HH);
        bool vx0 = (xi0 >= 0) && (xi0 < WW), vx1 = (xi1 >= 0) && (xi1 < WW);
        float hy = 1.f - ly, hx = 1.f - lx;
        float w00 = (vy0 && vx0) ? hy*hx*m : 0.f;
        float w01 = (vy0 && vx1) ? hy*lx*m : 0.f;
        float w10 = (vy1 && vx0) ? ly*hx*m : 0.f;
        float w11 = (vy1 && vx1) ? ly*lx*m : 0.f;
        int yc0 = min(max(y0, 0), HH-1), yc1 = min(max(y1, 0), HH-1);
        int xc0 = min(max(xi0, 0), WW-1), xc1 = min(max(xi1, 0), WW-1);
        const float4* p00 = (const float4*)(xt + ((b*HH + yc0)*WW + xc0)*CIN);
        const float4* p01 = (const float4*)(xt + ((b*HH + yc0)*WW + xc1)*CIN);
        const float4* p10 = (const float4*)(xt + ((b*HH + yc1)*WW + xc0)*CIN);
        const float4* p11 = (const float4*)(xt + ((b*HH + yc1)*WW + xc1)*CIN);
        int cb0 = grp * 4;          // this grp covers channels grp*16 .. +16
#pragma unroll
        for (int j = 0; j < 4; ++j) {
            float4 a = p00[cb0+j], b4 = p01[cb0+j], c4 = p10[cb0+j], d4 = p11[cb0+j];
            float rx = a.x*w00 + b4.x*w01 + c4.x*w10 + d4.x*w11;
            float ry = a.y*w00 + b4.y*w01 + c4.y*w10 + d4.y*w11;
            float rz = a.z*w00 + b4.z*w01 + c4.z*w10 + d4.z*w11;
            float rw = a.w*w00 + b4.w*w01 + c4.w*w10 + d4.w*w11;
            int c = grp*16 + j*4;
            samp[(c+0)*65 + px] = rx;
            samp[(c+1)*65 + px] = ry;
            samp[(c+2)*65 + px] = rz;
            samp[(c+3)*65 + px] = rw;
        }
        __syncthreads();

        // ---- phase 2: acc[o] += samp[c][px] * wt[k][c][og*32+o]
        const float* wk = wt + k*CIN*CO + og*32;
#pragma unroll 4
        for (int c = 0; c < 64; ++c) {
            float s = samp[c*65 + px];
            const float* wr = wk + c*CO;    // uniform -> s_load
#pragma unroll
            for (int o = 0; o < 32; ++o)
                acc[o] += s * wr[o];
        }
        __syncthreads();
    }

#pragma unroll
    for (int o = 0; o < 32; ++o)
        out[((b*CO + og*32 + o)*HH + ho)*WW + wo] = acc[o];
}

// ---------------------------------------------------------------------------
extern "C" void kernel_launch(void* const* d_in, const int* in_sizes, int n_in,
                              void* d_out, int out_size, void* d_ws, size_t ws_size,
                              hipStream_t stream) {
    const float* x  = (const float*)d_in[0];
    const float* ow = (const float*)d_in[1];
    const float* ob = (const float*)d_in[2];
    const float* wm = (const float*)d_in[3];
    float* outp = (float*)d_out;

    float* ws   = (float*)d_ws;
    float* xt   = ws + XT_OFF;
    float* tap  = ws + TAP_OFF;
    float* owt2 = ws + OWT_OFF;
    float* wt   = ws + WT_OFF;

    k_transpose_x<<<1024, 256, 0, stream>>>(x, xt);
    k_prep_w<<<349, 256, 0, stream>>>(ow, wm, owt2, wt);
    k_offconv<<<256, 256, 0, stream>>>(xt, owt2, ob, tap);
    k_main<<<1024, 256, 0, stream>>>(xt, tap, wt, outp);
}

// Round 4
// 165.721 us; speedup vs baseline: 1.9247x; 1.9247x over previous
//
#include <hip/hip_runtime.h>
#include <math.h>

// Problem constants
#define BB   4
#define CIN  64
#define HH   64
#define WW   256
#define CO   128
#define NPIX (BB*HH*WW)       // 65536

typedef float  f32x4 __attribute__((ext_vector_type(4)));
typedef unsigned int u32x4 __attribute__((ext_vector_type(4)));
typedef __bf16 bf16x8 __attribute__((ext_vector_type(8)));

// Workspace layout (float offsets). Total ~24.07 MB.
#define XT_OFF  0
#define XT_SZ   (BB*HH*WW*CIN)        // 4194304  x as [b][y][x][c] fp32
#define TAP_OFF (XT_OFF + XT_SZ)
#define TAP_SZ  (27*NPIX)             // 1769472  planes: dy[9], dx[9], mask[9]
#define OWT_OFF (TAP_OFF + TAP_SZ)
#define OWT_SZ  (9*CIN*28)            // 16128    offset-weight [t][c][28] fp32 (28-pad)
#define WTF_OFF (OWT_OFF + OWT_SZ)
#define WTF_SZF (9*4096)              // ushort[9][8192] bf16, A-frag order, XOR-swizzled

// ---------------------------------------------------------------------------
// K0x: x [B][C][H][W] -> xt [B][H][W][C]  (LDS tile transpose)
__global__ __launch_bounds__(256) void k_transpose_x(const float* __restrict__ x,
                                                     float* __restrict__ xt) {
    __shared__ float t[64][65];
    int bx = blockIdx.x;           // 1024 blocks: (b, y, xtile)
    int x0 = (bx & 3) * 64;
    int y  = (bx >> 2) & 63;
    int b  = bx >> 8;
    int tid = threadIdx.x;
    int lx = tid & 63, gy = tid >> 6;
#pragma unroll
    for (int i = 0; i < 16; ++i) {
        int c = i * 4 + gy;
        t[c][lx] = x[((b*CIN + c)*HH + y)*WW + x0 + lx];
    }
    __syncthreads();
#pragma unroll
    for (int i = 0; i < 16; ++i) {
        int xx = i * 4 + gy;
        xt[(((b*HH + y)*WW) + x0 + xx)*CIN + lx] = t[lx][xx];
    }
}

// ---------------------------------------------------------------------------
// K0w: weight prep.
//  owt2[t][c][28]: fp32, padded col 27 = 0
//  wtF [k][ (o*64+c) ^ ((o&7)<<3) ]: bf16, A-fragment rows pre-swizzled
__global__ __launch_bounds__(256) void k_prep_w(const float* __restrict__ ow,
                                                const float* __restrict__ wm,
                                                float* __restrict__ owt2,
                                                unsigned short* __restrict__ wtF) {
    const int n1 = 9*CIN*28;
    const int n2 = 9*CO*CIN;
    for (int i = blockIdx.x*blockDim.x + threadIdx.x;
         i < n1 + n2; i += gridDim.x*blockDim.x) {
        if (i < n1) {
            int t = i / (CIN*28);
            int r = i % (CIN*28);
            int c = r / 28, oc = r % 28;
            owt2[i] = (oc < 27) ? ow[(oc*CIN + c)*9 + t] : 0.f;
        } else {
            int j = i - n1;
            int k = j / (CO*CIN);
            int r = j % (CO*CIN);      // r = o*64 + c
            int o = r / CIN, c = r % CIN;
            float v = wm[(o*CIN + c)*9 + k];
            unsigned int u = __builtin_bit_cast(unsigned int, v);
            u += 0x7FFF + ((u >> 16) & 1);          // RNE to bf16
            wtF[k*8192 + (r ^ ((o & 7) << 3))] = (unsigned short)(u >> 16);
        }
    }
}

// ---------------------------------------------------------------------------
// K1: offset conv (fp32 for offset precision). 1024 blocks = 64px x 4 oc-groups.
__global__ __launch_bounds__(256) void k_offconv(const float* __restrict__ xt,
                                                 const float* __restrict__ owt2,
                                                 const float* __restrict__ ob,
                                                 float* __restrict__ tap) {
    int bx = blockIdx.x;
    int wtile = bx & 3, ho = (bx >> 2) & 63, b = bx >> 8;
    int tid = threadIdx.x;
    int px = tid & 63;
    int g = __builtin_amdgcn_readfirstlane(tid >> 6);   // wave-uniform oc-group
    int wo = wtile*64 + px;

    float acc[7];
#pragma unroll
    for (int i = 0; i < 7; ++i) {
        int oc = g*7 + i;
        acc[i] = (oc < 27) ? ob[oc] : 0.f;
    }

    for (int t = 0; t < 9; ++t) {
        int y = ho + t/3 - 1;
        if (y < 0 || y >= HH) continue;
        int xx = wo + t%3 - 1;
        bool vx = (xx >= 0) && (xx < WW);
        const f32x4* p = (const f32x4*)(xt + (((b*HH + y)*WW) + (vx ? xx : 0))*CIN);
        const float* wp = owt2 + t*CIN*28 + g*7;   // uniform base -> s_load
#pragma unroll
        for (int cb = 0; cb < 16; ++cb) {
            f32x4 v = p[cb];
            if (!vx) v = (f32x4){0.f, 0.f, 0.f, 0.f};
#pragma unroll
            for (int i = 0; i < 7; ++i) {
                acc[i] += v.x * wp[(cb*4+0)*28 + i];
                acc[i] += v.y * wp[(cb*4+1)*28 + i];
                acc[i] += v.z * wp[(cb*4+2)*28 + i];
                acc[i] += v.w * wp[(cb*4+3)*28 + i];
            }
        }
    }

    int gpix = (b*HH + ho)*WW + wo;
#pragma unroll
    for (int i = 0; i < 7; ++i) {
        int oc = g*7 + i;
        if (oc < 27) {
            float vv = acc[i];
            int plane;
            if (oc < 18) plane = (oc & 1)*9 + (oc >> 1);       // dy planes 0-8, dx 9-17
            else { plane = oc; vv = 1.f / (1.f + __expf(-vv)); }  // mask 18-26, sigmoid
            tap[plane*NPIX + gpix] = vv;
        }
    }
}

// ---------------------------------------------------------------------------
// K2: fused deformable sampling + bf16 MFMA GEMM.
// Block = 4 waves; wave = 128(o) x 16(px) output tile. Lane l: px=l&15, hi=l>>4.
// B-fragments come straight out of bilinear sampling (no LDS for activations).
// A (weights) staged in LDS per tap (16 KB, XOR-swizzled layout baked in global),
// with register double-buffer prefetch of the next tap.
__global__ __launch_bounds__(256) void k_main(const float* __restrict__ xt,
                                              const float* __restrict__ tap,
                                              const unsigned short* __restrict__ wtF,
                                              float* __restrict__ out) {
    __shared__ u32x4 wlds[1024];   // 16 KB: wtT[o=128][c=64] bf16, swizzled
    int bx = blockIdx.x;
    int wtile = bx & 3, ho = (bx >> 2) & 63, b = bx >> 8;
    int tid = threadIdx.x;
    int w = tid >> 6;
    int l = tid & 63;
    int pxl = l & 15, hi = l >> 4;
    int wo = wtile*64 + w*16 + pxl;
    int gpix = (b*HH + ho)*WW + wo;

    // A-fragment swizzled LDS byte offsets: addr = pxl*128 + mi*2048 + lo_s
    int lo0 = (hi*16)      ^ ((l & 7) << 4);
    int lo1 = (64 + hi*16) ^ ((l & 7) << 4);
    int abase = pxl * 128;

    const u32x4* wsrc = (const u32x4*)wtF;
    u32x4 wr0 = wsrc[tid], wr1 = wsrc[tid+256], wr2 = wsrc[tid+512], wr3 = wsrc[tid+768];

    f32x4 acc[8];
#pragma unroll
    for (int i = 0; i < 8; ++i) acc[i] = (f32x4){0.f, 0.f, 0.f, 0.f};

    for (int k = 0; k < 9; ++k) {
        __syncthreads();                    // prev tap's A-reads done
        wlds[tid] = wr0; wlds[tid+256] = wr1; wlds[tid+512] = wr2; wlds[tid+768] = wr3;
        __syncthreads();
        if (k < 8) {                        // prefetch next tap's A (hidden under compute)
            const u32x4* ws2 = wsrc + (k+1)*1024;
            wr0 = ws2[tid]; wr1 = ws2[tid+256]; wr2 = ws2[tid+512]; wr3 = ws2[tid+768];
        }

        // ---- bilinear sampling -> B fragments (in-register)
        float dy = tap[k*NPIX + gpix];
        float dx = tap[(9+k)*NPIX + gpix];
        float m  = tap[(18+k)*NPIX + gpix];
        int ki = k / 3, kj = k - ki*3;
        float py  = dy + (float)(ho - 1 + ki);
        float pxf = dx + (float)(wo - 1 + kj);
        float y0f = floorf(py), x0f = floorf(pxf);
        float ly = py - y0f, lx = pxf - x0f;
        int y0 = (int)y0f, x0 = (int)x0f;
        int y1 = y0 + 1,  x1 = x0 + 1;
        bool vy0 = (y0 >= 0) && (y0 < HH), vy1 = (y1 >= 0) && (y1 < HH);
        bool vx0 = (x0 >= 0) && (x0 < WW), vx1 = (x1 >= 0) && (x1 < WW);
        float hy = 1.f - ly, hx = 1.f - lx;
        float w00 = (vy0 && vx0) ? hy*hx*m : 0.f;
        float w01 = (vy0 && vx1) ? hy*lx*m : 0.f;
        float w10 = (vy1 && vx0) ? ly*hx*m : 0.f;
        float w11 = (vy1 && vx1) ? ly*lx*m : 0.f;
        int yc0 = min(max(y0, 0), HH-1), yc1 = min(max(y1, 0), HH-1);
        int xc0 = min(max(x0, 0), WW-1), xc1 = min(max(x1, 0), WW-1);
        const float* p00 = xt + ((b*HH + yc0)*WW + xc0)*CIN;
        const float* p01 = xt + ((b*HH + yc0)*WW + xc1)*CIN;
        const float* p10 = xt + ((b*HH + yc1)*WW + xc0)*CIN;
        const float* p11 = xt + ((b*HH + yc1)*WW + xc1)*CIN;

        bf16x8 bf0, bf1;
#pragma unroll
        for (int q = 0; q < 2; ++q) {
            int co = hi*8 + q*4;
            {
                f32x4 a0 = *(const f32x4*)(p00 + co);
                f32x4 a1 = *(const f32x4*)(p01 + co);
                f32x4 a2 = *(const f32x4*)(p10 + co);
                f32x4 a3 = *(const f32x4*)(p11 + co);
                f32x4 r = a0*w00 + a1*w01 + a2*w10 + a3*w11;
                bf0[q*4+0] = (__bf16)r.x; bf0[q*4+1] = (__bf16)r.y;
                bf0[q*4+2] = (__bf16)r.z; bf0[q*4+3] = (__bf16)r.w;
            }
            {
                f32x4 a0 = *(const f32x4*)(p00 + 32 + co);
                f32x4 a1 = *(const f32x4*)(p01 + 32 + co);
                f32x4 a2 = *(const f32x4*)(p10 + 32 + co);
                f32x4 a3 = *(const f32x4*)(p11 + 32 + co);
                f32x4 r = a0*w00 + a1*w01 + a2*w10 + a3*w11;
                bf1[q*4+0] = (__bf16)r.x; bf1[q*4+1] = (__bf16)r.y;
                bf1[q*4+2] = (__bf16)r.z; bf1[q*4+3] = (__bf16)r.w;
            }
        }

        // ---- MFMA: acc[mi] += A(tap k, o-frag mi) x B
#pragma unroll
        for (int mi = 0; mi < 8; ++mi) {
            u32x4 a0 = *(const u32x4*)((const char*)wlds + (abase + lo0 + mi*2048));
            u32x4 a1 = *(const u32x4*)((const char*)wlds + (abase + lo1 + mi*2048));
            acc[mi] = __builtin_amdgcn_mfma_f32_16x16x32_bf16(
                          __builtin_bit_cast(bf16x8, a0), bf0, acc[mi], 0, 0, 0);
            acc[mi] = __builtin_amdgcn_mfma_f32_16x16x32_bf16(
                          __builtin_bit_cast(bf16x8, a1), bf1, acc[mi], 0, 0, 0);
        }
    }

#pragma unroll
    for (int mi = 0; mi < 8; ++mi) {
#pragma unroll
        for (int r = 0; r < 4; ++r) {
            int o = mi*16 + hi*4 + r;     // C/D: col=lane&15(px), row=(lane>>4)*4+reg
            out[((b*CO + o)*HH + ho)*WW + wo] = acc[mi][r];
        }
    }
}

// ---------------------------------------------------------------------------
extern "C" void kernel_launch(void* const* d_in, const int* in_sizes, int n_in,
                              void* d_out, int out_size, void* d_ws, size_t ws_size,
                              hipStream_t stream) {
    const float* x  = (const float*)d_in[0];
    const float* ow = (const float*)d_in[1];
    const float* ob = (const float*)d_in[2];
    const float* wm = (const float*)d_in[3];
    float* outp = (float*)d_out;

    float* ws   = (float*)d_ws;
    float* xt   = ws + XT_OFF;
    float* tap  = ws + TAP_OFF;
    float* owt2 = ws + OWT_OFF;
    unsigned short* wtF = (unsigned short*)(ws + WTF_OFF);

    k_transpose_x<<<1024, 256, 0, stream>>>(x, xt);
    k_prep_w<<<352, 256, 0, stream>>>(ow, wm, owt2, wtF);
    k_offconv<<<1024, 256, 0, stream>>>(xt, owt2, ob, tap);
    k_main<<<1024, 256, 0, stream>>>(xt, tap, wtF, outp);
}

// Round 6
// 109.523 us; speedup vs baseline: 2.9122x; 1.5131x over previous
//
#include <hip/hip_runtime.h>
#include <math.h>

// Problem constants
#define BB   4
#define CIN  64
#define HH   64
#define WW   256
#define CO   128
#define NPIX (BB*HH*WW)       // 65536

typedef float  f32x4 __attribute__((ext_vector_type(4)));
typedef unsigned int u32x4 __attribute__((ext_vector_type(4)));
typedef __bf16 bf16x8 __attribute__((ext_vector_type(8)));
typedef __bf16 bf16x2 __attribute__((ext_vector_type(2)));

// Workspace layout (float/u32 slots). Total ~15.6 MB.
#define XTB_OFF  0
#define XTB_SZ   (NPIX*32)            // 2097152 u32: bf16 x as [b][y][x][c], 2ch/u32
#define TAP_OFF  (XTB_OFF + XTB_SZ)
#define TAP_SZ   (27*NPIX)            // planes: dy[9], dx[9], mask[9] (f32)
#define OWT_OFF  (TAP_OFF + TAP_SZ)
#define OWT_SZ   (9*CIN*32)           // 18432 f32: offset-w [t][c][32] (27 used, pad 0)
#define WTF_OFF  (OWT_OFF + OWT_SZ)   // ushort[9][8192] bf16 A-frag, XOR-swizzled

// ---------------------------------------------------------------------------
// K0x: x [B][C][H][W] f32 -> xtb [B][H][W][C] bf16 (packed 2ch/u32, linear order)
__global__ __launch_bounds__(256) void k_transpose_x(const float* __restrict__ x,
                                                     unsigned int* __restrict__ xtb) {
    __shared__ float t[64][65];
    int bx = blockIdx.x;           // 1024 blocks: (b, y, xtile)
    int x0 = (bx & 3) * 64;
    int y  = (bx >> 2) & 63;
    int b  = bx >> 8;
    int tid = threadIdx.x;
    int lx = tid & 63, gy = tid >> 6;
#pragma unroll
    for (int i = 0; i < 16; ++i) {
        int c = i * 4 + gy;
        t[c][lx] = x[((b*CIN + c)*HH + y)*WW + x0 + lx];
    }
    __syncthreads();
    int px = tid & 63, cg = tid >> 6;      // 16 channels per cg
    u32x4 r0, r1;
#pragma unroll
    for (int j = 0; j < 4; ++j) {
        bf16x2 p, q;
        p[0] = (__bf16)t[cg*16 + 2*j][px];
        p[1] = (__bf16)t[cg*16 + 2*j + 1][px];
        q[0] = (__bf16)t[cg*16 + 8 + 2*j][px];
        q[1] = (__bf16)t[cg*16 + 8 + 2*j + 1][px];
        r0[j] = __builtin_bit_cast(unsigned int, p);
        r1[j] = __builtin_bit_cast(unsigned int, q);
    }
    u32x4* dst = (u32x4*)(xtb + (((b*HH + y)*WW) + x0 + px)*32 + cg*8);
    dst[0] = r0; dst[1] = r1;
}

// ---------------------------------------------------------------------------
// K0w: weight prep.
//  owt3[t][c][32]: fp32, cols 27..31 = 0
//  wtF [k][ (o*64+c) ^ ((o&7)<<3) ]: bf16, A-fragment rows pre-swizzled
__global__ __launch_bounds__(256) void k_prep_w(const float* __restrict__ ow,
                                                const float* __restrict__ wm,
                                                float* __restrict__ owt3,
                                                unsigned short* __restrict__ wtF) {
    const int n1 = 9*CIN*32;
    const int n2 = 9*CO*CIN;
    for (int i = blockIdx.x*blockDim.x + threadIdx.x;
         i < n1 + n2; i += gridDim.x*blockDim.x) {
        if (i < n1) {
            int t = i / (CIN*32);
            int r = i % (CIN*32);
            int c = r / 32, oc = r % 32;
            owt3[i] = (oc < 27) ? ow[(oc*CIN + c)*9 + t] : 0.f;
        } else {
            int j = i - n1;
            int k = j / (CO*CIN);
            int r = j % (CO*CIN);      // r = o*64 + c
            int o = r / CIN, c = r % CIN;
            float v = wm[(o*CIN + c)*9 + k];
            unsigned int u = __builtin_bit_cast(unsigned int, v);
            u += 0x7FFF + ((u >> 16) & 1);          // RNE to bf16
            wtF[k*8192 + (r ^ ((o & 7) << 3))] = (unsigned short)(u >> 16);
        }
    }
}

// ---------------------------------------------------------------------------
// K1: offset conv. 512 blocks x 512 threads: 128 px x 4 oc-groups (8 oc each).
// Weights in LDS [t][c][32] (wave-uniform ds_read_b128 broadcast, no s_load stalls).
__global__ __launch_bounds__(512) void k_offconv(const unsigned int* __restrict__ xtb,
                                                 const float* __restrict__ owt3,
                                                 const float* __restrict__ ob,
                                                 float* __restrict__ tap) {
    __shared__ float wsh[9*CIN*32];    // 73728 B
    int bx = blockIdx.x;               // 512: b(2) ho(6) wt(1)
    int wt2 = bx & 1, ho = (bx >> 1) & 63, b = bx >> 7;
    int tid = threadIdx.x;
    {
        const f32x4* src = (const f32x4*)owt3;
        f32x4* dst = (f32x4*)wsh;
#pragma unroll
        for (int i = 0; i < 9; ++i) dst[tid + i*512] = src[tid + i*512];
    }
    __syncthreads();
    int px = tid & 127;
    int g = __builtin_amdgcn_readfirstlane(tid >> 7);   // wave-uniform oc-group
    int wo = wt2*128 + px;

    float acc[8];
#pragma unroll
    for (int i = 0; i < 8; ++i) { int oc = g*8 + i; acc[i] = (oc < 27) ? ob[oc] : 0.f; }

    for (int t = 0; t < 9; ++t) {
        int y = ho + t/3 - 1;
        if (y < 0 || y >= HH) continue;
        int xx = wo + t%3 - 1;
        bool vx = (xx >= 0) && (xx < WW);
        const u32x4* p = (const u32x4*)(xtb + ((b*HH + y)*WW + (vx ? xx : 0))*32);
        const float* wb = wsh + t*CIN*32 + g*8;
#pragma unroll
        for (int cb = 0; cb < 8; ++cb) {
            u32x4 v = p[cb];
            if (!vx) v = (u32x4){0u, 0u, 0u, 0u};
#pragma unroll
            for (int j = 0; j < 4; ++j) {
                float xlo = __builtin_bit_cast(float, v[j] << 16);
                float xhi = __builtin_bit_cast(float, v[j] & 0xFFFF0000u);
                int c0 = cb*8 + 2*j;
                f32x4 wa  = *(const f32x4*)(wb + c0*32);
                f32x4 wb4 = *(const f32x4*)(wb + c0*32 + 4);
                f32x4 wc  = *(const f32x4*)(wb + (c0+1)*32);
                f32x4 wd  = *(const f32x4*)(wb + (c0+1)*32 + 4);
                acc[0] += xlo*wa.x;  acc[1] += xlo*wa.y;  acc[2] += xlo*wa.z;  acc[3] += xlo*wa.w;
                acc[4] += xlo*wb4.x; acc[5] += xlo*wb4.y; acc[6] += xlo*wb4.z; acc[7] += xlo*wb4.w;
                acc[0] += xhi*wc.x;  acc[1] += xhi*wc.y;  acc[2] += xhi*wc.z;  acc[3] += xhi*wc.w;
                acc[4] += xhi*wd.x;  acc[5] += xhi*wd.y;  acc[6] += xhi*wd.z;  acc[7] += xhi*wd.w;
            }
        }
    }

    int gpix = (b*HH + ho)*WW + wo;
#pragma unroll
    for (int i = 0; i < 8; ++i) {
        int oc = g*8 + i;
        if (oc < 27) {
            float vv = acc[i];
            int plane;
            if (oc < 18) plane = (oc & 1)*9 + (oc >> 1);          // dy 0-8, dx 9-17
            else { plane = oc; vv = 1.f / (1.f + __expf(-vv)); }  // mask 18-26
            tap[plane*NPIX + gpix] = vv;
        }
    }
}

// ---------------------------------------------------------------------------
// bf16x8 bilinear lerp: 4 corners of 8 packed-bf16 channels, f32 math, bf16 out
__device__ inline bf16x8 lerp8(u32x4 a, u32x4 b, u32x4 c, u32x4 d,
                               float w0, float w1, float w2, float w3) {
    bf16x8 r;
#pragma unroll
    for (int j = 0; j < 4; ++j) {
        float alo = __builtin_bit_cast(float, a[j] << 16);
        float ahi = __builtin_bit_cast(float, a[j] & 0xFFFF0000u);
        float blo = __builtin_bit_cast(float, b[j] << 16);
        float bhi = __builtin_bit_cast(float, b[j] & 0xFFFF0000u);
        float clo = __builtin_bit_cast(float, c[j] << 16);
        float chi = __builtin_bit_cast(float, c[j] & 0xFFFF0000u);
        float dlo = __builtin_bit_cast(float, d[j] << 16);
        float dhi = __builtin_bit_cast(float, d[j] & 0xFFFF0000u);
        float rlo = alo*w0 + blo*w1 + clo*w2 + dlo*w3;
        float rhi = ahi*w0 + bhi*w1 + chi*w2 + dhi*w3;
        r[2*j]   = (__bf16)rlo;
        r[2*j+1] = (__bf16)rhi;
    }
    return r;
}

// ---------------------------------------------------------------------------
// K2: fused deformable sampling + bf16 MFMA GEMM.
// Wave = 128(o) x 16(px). Lane l: px=l&15, hi=l>>4; bf16 gathers: 8 x 16B per tap.
// Weights: LDS double-buffer (2 x 16KB), ONE barrier per tap.
__global__ __launch_bounds__(256) void k_main(const unsigned int* __restrict__ xtb,
                                              const float* __restrict__ tap,
                                              const unsigned short* __restrict__ wtF,
                                              float* __restrict__ out) {
    __shared__ u32x4 wlds[2048];   // 32 KB: two 16KB buffers
    int bx = blockIdx.x;
    int wtile = bx & 3, ho = (bx >> 2) & 63, b = bx >> 8;
    int tid = threadIdx.x;
    int w = tid >> 6;
    int l = tid & 63;
    int pxl = l & 15, hi = l >> 4;
    int wo = wtile*64 + w*16 + pxl;
    int gpix = (b*HH + ho)*WW + wo;

    // A-fragment swizzled LDS byte offsets (within a 16KB buffer)
    int lo0 = (hi*16)      ^ ((l & 7) << 4);
    int lo1 = (64 + hi*16) ^ ((l & 7) << 4);
    int abase = pxl * 128;

    // hoist all tap params (27 independent loads, one latency)
    float tdy[9], tdx[9], tm[9];
#pragma unroll
    for (int k = 0; k < 9; ++k) {
        tdy[k] = tap[k*NPIX + gpix];
        tdx[k] = tap[(9+k)*NPIX + gpix];
        tm[k]  = tap[(18+k)*NPIX + gpix];
    }

    const u32x4* wsrc = (const u32x4*)wtF;
    {   // stage tap 0 into buffer 0
        u32x4 s0 = wsrc[tid], s1 = wsrc[tid+256], s2 = wsrc[tid+512], s3 = wsrc[tid+768];
        wlds[tid] = s0; wlds[tid+256] = s1; wlds[tid+512] = s2; wlds[tid+768] = s3;
    }
    __syncthreads();

    f32x4 acc[8];
#pragma unroll
    for (int i = 0; i < 8; ++i) acc[i] = (f32x4){0.f, 0.f, 0.f, 0.f};

#pragma unroll
    for (int k = 0; k < 9; ++k) {
        // issue next tap's staging loads early (T14: latency hides under compute)
        u32x4 s0, s1, s2, s3;
        if (k < 8) {
            const u32x4* ws2 = wsrc + (k+1)*1024;
            s0 = ws2[tid]; s1 = ws2[tid+256]; s2 = ws2[tid+512]; s3 = ws2[tid+768];
        }

        // ---- bilinear sampling -> B fragments (bf16 gathers, f32 lerp)
        float dy = tdy[k], dx = tdx[k], m = tm[k];
        int ki = k / 3, kj = k - ki*3;
        float py  = dy + (float)(ho - 1 + ki);
        float pxf = dx + (float)(wo - 1 + kj);
        float y0f = floorf(py), x0f = floorf(pxf);
        float ly = py - y0f, lxf = pxf - x0f;
        int y0 = (int)y0f, x0 = (int)x0f;
        int y1 = y0 + 1,  x1 = x0 + 1;
        bool vy0 = (y0 >= 0) && (y0 < HH), vy1 = (y1 >= 0) && (y1 < HH);
        bool vx0 = (x0 >= 0) && (x0 < WW), vx1 = (x1 >= 0) && (x1 < WW);
        float hy = 1.f - ly, hx = 1.f - lxf;
        float w00 = (vy0 && vx0) ? hy*hx*m : 0.f;
        float w01 = (vy0 && vx1) ? hy*lxf*m : 0.f;
        float w10 = (vy1 && vx0) ? ly*hx*m : 0.f;
        float w11 = (vy1 && vx1) ? ly*lxf*m : 0.f;
        int yc0 = min(max(y0, 0), HH-1), yc1 = min(max(y1, 0), HH-1);
        int xc0 = min(max(x0, 0), WW-1), xc1 = min(max(x1, 0), WW-1);
        const u32x4* p00 = (const u32x4*)(xtb + ((b*HH + yc0)*WW + xc0)*32);
        const u32x4* p01 = (const u32x4*)(xtb + ((b*HH + yc0)*WW + xc1)*32);
        const u32x4* p10 = (const u32x4*)(xtb + ((b*HH + yc1)*WW + xc0)*32);
        const u32x4* p11 = (const u32x4*)(xtb + ((b*HH + yc1)*WW + xc1)*32);

        u32x4 g00 = p00[hi],   g01 = p01[hi],   g10 = p10[hi],   g11 = p11[hi];
        u32x4 h00 = p00[hi+4], h01 = p01[hi+4], h10 = p10[hi+4], h11 = p11[hi+4];
        bf16x8 bf0 = lerp8(g00, g01, g10, g11, w00, w01, w10, w11);
        bf16x8 bf1 = lerp8(h00, h01, h10, h11, w00, w01, w10, w11);

        // ---- MFMA from current buffer
        const char* wb = (const char*)wlds + (k & 1)*16384;
#pragma unroll
        for (int mi = 0; mi < 8; ++mi) {
            u32x4 a0 = *(const u32x4*)(wb + (abase + lo0 + mi*2048));
            u32x4 a1 = *(const u32x4*)(wb + (abase + lo1 + mi*2048));
            acc[mi] = __builtin_amdgcn_mfma_f32_16x16x32_bf16(
                          __builtin_bit_cast(bf16x8, a0), bf0, acc[mi], 0, 0, 0);
            acc[mi] = __builtin_amdgcn_mfma_f32_16x16x32_bf16(
                          __builtin_bit_cast(bf16x8, a1), bf1, acc[mi], 0, 0, 0);
        }

        // ---- write next buffer, single barrier per tap
        if (k < 8) {
            u32x4* nb = wlds + ((k+1) & 1)*1024;
            nb[tid] = s0; nb[tid+256] = s1; nb[tid+512] = s2; nb[tid+768] = s3;
        }
        __syncthreads();
    }

#pragma unroll
    for (int mi = 0; mi < 8; ++mi) {
#pragma unroll
        for (int r = 0; r < 4; ++r) {
            int o = mi*16 + hi*4 + r;     // C/D: col=lane&15(px), row=(lane>>4)*4+reg
            out[((b*CO + o)*HH + ho)*WW + wo] = acc[mi][r];
        }
    }
}

// ---------------------------------------------------------------------------
extern "C" void kernel_launch(void* const* d_in, const int* in_sizes, int n_in,
                              void* d_out, int out_size, void* d_ws, size_t ws_size,
                              hipStream_t stream) {
    const float* x  = (const float*)d_in[0];
    const float* ow = (const float*)d_in[1];
    const float* ob = (const float*)d_in[2];
    const float* wm = (const float*)d_in[3];
    float* outp = (float*)d_out;

    float* ws   = (float*)d_ws;
    unsigned int* xtb = (unsigned int*)(ws + XTB_OFF);
    float* tap  = ws + TAP_OFF;
    float* owt3 = ws + OWT_OFF;
    unsigned short* wtF = (unsigned short*)(ws + WTF_OFF);

    k_transpose_x<<<1024, 256, 0, stream>>>(x, xtb);
    k_prep_w<<<360, 256, 0, stream>>>(ow, wm, owt3, wtF);
    k_offconv<<<512, 512, 0, stream>>>(xtb, owt3, ob, tap);
    k_main<<<1024, 256, 0, stream>>>(xtb, tap, wtF, outp);
}

// Round 7
// 76.321 us; speedup vs baseline: 4.1792x; 1.4350x over previous
//
#include <hip/hip_runtime.h>
#include <math.h>

// Problem constants
#define BB   4
#define CIN  64
#define HH   64
#define WW   256
#define CO   128
#define NPIX (BB*HH*WW)       // 65536

typedef float  f32x4 __attribute__((ext_vector_type(4)));
typedef unsigned int u32x4 __attribute__((ext_vector_type(4)));
typedef __bf16 bf16x8 __attribute__((ext_vector_type(8)));
typedef __bf16 bf16x2 __attribute__((ext_vector_type(2)));

// Workspace layout (float/u32 slots). Total ~15.7 MB.
#define XTB_OFF  0
#define XTB_SZ   (NPIX*32)            // 2097152 u32: bf16 x as [b][y][x][c], 2ch/u32
#define TAP_OFF  (XTB_OFF + XTB_SZ)
#define TAP_SZ   (27*NPIX)            // planes: dy[9], dx[9], mask[9] (f32)
#define OWB_OFF  (TAP_OFF + TAP_SZ)
#define OWB_SZ   9216                 // 18432 bf16: offconv A-fragments [18][2][64][8]
#define WTF_OFF  (OWB_OFF + OWB_SZ)   // ushort[9][8192] bf16 A-frag, XOR-swizzled

// ---------------------------------------------------------------------------
// K0x: x [B][C][H][W] f32 -> xtb [B][H][W][C] bf16 (packed 2ch/u32, linear order)
__global__ __launch_bounds__(256) void k_transpose_x(const float* __restrict__ x,
                                                     unsigned int* __restrict__ xtb) {
    __shared__ float t[64][65];
    int bx = blockIdx.x;           // 1024 blocks: (b, y, xtile)
    int x0 = (bx & 3) * 64;
    int y  = (bx >> 2) & 63;
    int b  = bx >> 8;
    int tid = threadIdx.x;
    int lx = tid & 63, gy = tid >> 6;
#pragma unroll
    for (int i = 0; i < 16; ++i) {
        int c = i * 4 + gy;
        t[c][lx] = x[((b*CIN + c)*HH + y)*WW + x0 + lx];
    }
    __syncthreads();
    int px = tid & 63, cg = tid >> 6;      // 16 channels per cg
    u32x4 r0, r1;
#pragma unroll
    for (int j = 0; j < 4; ++j) {
        bf16x2 p, q;
        p[0] = (__bf16)t[cg*16 + 2*j][px];
        p[1] = (__bf16)t[cg*16 + 2*j + 1][px];
        q[0] = (__bf16)t[cg*16 + 8 + 2*j][px];
        q[1] = (__bf16)t[cg*16 + 8 + 2*j + 1][px];
        r0[j] = __builtin_bit_cast(unsigned int, p);
        r1[j] = __builtin_bit_cast(unsigned int, q);
    }
    u32x4* dst = (u32x4*)(xtb + (((b*HH + y)*WW) + x0 + px)*32 + cg*8);
    dst[0] = r0; dst[1] = r1;
}

// ---------------------------------------------------------------------------
// K0w: weight prep.
//  owb: offconv weights as bf16 A-fragments. elem e = ((kk*2+mi)*64+l)*8+j holds
//       W[oc=mi*16+(l&15)][k=kk*32+(l>>4)*8+j], k=t*64+c, 0 for oc>=27.
//  wtF [k][ (o*64+c) ^ ((o&7)<<3) ]: bf16, A-fragment rows pre-swizzled
__global__ __launch_bounds__(256) void k_prep_w(const float* __restrict__ ow,
                                                const float* __restrict__ wm,
                                                unsigned short* __restrict__ owb,
                                                unsigned short* __restrict__ wtF) {
    const int n1 = 18432;
    const int n2 = 9*CO*CIN;
    for (int i = blockIdx.x*blockDim.x + threadIdx.x;
         i < n1 + n2; i += gridDim.x*blockDim.x) {
        if (i < n1) {
            int j = i & 7, l = (i >> 3) & 63, mi = (i >> 9) & 1, kk = i >> 10;
            int oc = mi*16 + (l & 15);
            int k  = kk*32 + (l >> 4)*8 + j;
            int t = k >> 6, c = k & 63;
            float v = (oc < 27) ? ow[(oc*CIN + c)*9 + t] : 0.f;
            unsigned int u = __builtin_bit_cast(unsigned int, v);
            u += 0x7FFF + ((u >> 16) & 1);          // RNE to bf16
            owb[i] = (unsigned short)(u >> 16);
        } else {
            int j = i - n1;
            int k = j / (CO*CIN);
            int r = j % (CO*CIN);      // r = o*64 + c
            int o = r / CIN, c = r % CIN;
            float v = wm[(o*CIN + c)*9 + k];
            unsigned int u = __builtin_bit_cast(unsigned int, v);
            u += 0x7FFF + ((u >> 16) & 1);          // RNE to bf16
            wtF[k*8192 + (r ^ ((o & 7) << 3))] = (unsigned short)(u >> 16);
        }
    }
}

// ---------------------------------------------------------------------------
// K1: offset conv via MFMA. 1024 blocks x 4 waves; wave = 32(oc) x 16(px) tile.
// B-fragments: fixed-tap reads of xtb (1 x 16B load / k-step); A staged in LDS.
__global__ __launch_bounds__(256) void k_offconv(const unsigned int* __restrict__ xtb,
                                                 const unsigned short* __restrict__ owb,
                                                 const float* __restrict__ ob,
                                                 float* __restrict__ tap) {
    __shared__ u32x4 awl[2304];        // 36864 B
    int bx = blockIdx.x;               // 1024: (b, ho, wtile)
    int wtile = bx & 3, ho = (bx >> 2) & 63, b = bx >> 8;
    int tid = threadIdx.x;
    {
        const u32x4* asrc = (const u32x4*)owb;
#pragma unroll
        for (int i = 0; i < 9; ++i) awl[tid + i*256] = asrc[tid + i*256];
    }
    __syncthreads();
    int w = tid >> 6, l = tid & 63;
    int pxl = l & 15, hi = l >> 4;
    int wo = wtile*64 + w*16 + pxl;

    f32x4 acc0 = (f32x4){0.f,0.f,0.f,0.f}, acc1 = (f32x4){0.f,0.f,0.f,0.f};
#pragma unroll
    for (int kk = 0; kk < 18; ++kk) {
        const int t = kk >> 1;
        const int ki = t / 3, kj = t % 3;
        int y  = ho + ki - 1;
        int xx = wo + kj - 1;
        bool v = (y >= 0) && (y < HH) && (xx >= 0) && (xx < WW);
        int yc = min(max(y, 0), HH-1), xc = min(max(xx, 0), WW-1);
        const u32x4* p = (const u32x4*)(xtb + ((b*HH + yc)*WW + xc)*32);
        u32x4 bv = p[(kk & 1)*4 + hi];
        if (!v) bv = (u32x4){0u,0u,0u,0u};
        u32x4 a0 = awl[(kk*2+0)*64 + l];
        u32x4 a1 = awl[(kk*2+1)*64 + l];
        acc0 = __builtin_amdgcn_mfma_f32_16x16x32_bf16(
                   __builtin_bit_cast(bf16x8, a0), __builtin_bit_cast(bf16x8, bv), acc0, 0, 0, 0);
        acc1 = __builtin_amdgcn_mfma_f32_16x16x32_bf16(
                   __builtin_bit_cast(bf16x8, a1), __builtin_bit_cast(bf16x8, bv), acc1, 0, 0, 0);
    }

    int gpix = (b*HH + ho)*WW + wo;
#pragma unroll
    for (int r = 0; r < 4; ++r) {
        int oc0 = hi*4 + r;                       // 0..15: dy/dx planes
        float v0 = acc0[r] + ob[oc0];
        int plane0 = (oc0 & 1)*9 + (oc0 >> 1);
        tap[plane0*NPIX + gpix] = v0;
        int oc1 = 16 + hi*4 + r;                  // 16..31
        if (oc1 < 27) {
            float v1 = acc1[r] + ob[oc1];
            float vv; int plane1;
            if (oc1 < 18) { plane1 = (oc1 & 1)*9 + (oc1 >> 1); vv = v1; }
            else { plane1 = oc1; vv = 1.f / (1.f + __expf(-v1)); }
            tap[plane1*NPIX + gpix] = vv;
        }
    }
}

// ---------------------------------------------------------------------------
// bf16x8 bilinear lerp: 4 corners of 8 packed-bf16 channels, f32 math, bf16 out
__device__ inline bf16x8 lerp8(u32x4 a, u32x4 b, u32x4 c, u32x4 d,
                               float w0, float w1, float w2, float w3) {
    bf16x8 r;
#pragma unroll
    for (int j = 0; j < 4; ++j) {
        float alo = __builtin_bit_cast(float, a[j] << 16);
        float ahi = __builtin_bit_cast(float, a[j] & 0xFFFF0000u);
        float blo = __builtin_bit_cast(float, b[j] << 16);
        float bhi = __builtin_bit_cast(float, b[j] & 0xFFFF0000u);
        float clo = __builtin_bit_cast(float, c[j] << 16);
        float chi = __builtin_bit_cast(float, c[j] & 0xFFFF0000u);
        float dlo = __builtin_bit_cast(float, d[j] << 16);
        float dhi = __builtin_bit_cast(float, d[j] & 0xFFFF0000u);
        float rlo = alo*w0 + blo*w1 + clo*w2 + dlo*w3;
        float rhi = ahi*w0 + bhi*w1 + chi*w2 + dhi*w3;
        r[2*j]   = (__bf16)rlo;
        r[2*j+1] = (__bf16)rhi;
    }
    return r;
}

// ---------------------------------------------------------------------------
// K2: fused deformable sampling + bf16 MFMA GEMM.
// Wave = 128(o) x 16(px). Lane l: px=l&15, hi=l>>4; bf16 gathers: 8 x 16B per tap.
// Weights: LDS double-buffer (2 x 16KB), ONE barrier per tap.
__global__ __launch_bounds__(256) void k_main(const unsigned int* __restrict__ xtb,
                                              const float* __restrict__ tap,
                                              const unsigned short* __restrict__ wtF,
                                              float* __restrict__ out) {
    __shared__ u32x4 wlds[2048];   // 32 KB: two 16KB buffers
    int bx = blockIdx.x;
    int wtile = bx & 3, ho = (bx >> 2) & 63, b = bx >> 8;
    int tid = threadIdx.x;
    int w = tid >> 6;
    int l = tid & 63;
    int pxl = l & 15, hi = l >> 4;
    int wo = wtile*64 + w*16 + pxl;
    int gpix = (b*HH + ho)*WW + wo;

    // A-fragment swizzled LDS byte offsets (within a 16KB buffer)
    int lo0 = (hi*16)      ^ ((l & 7) << 4);
    int lo1 = (64 + hi*16) ^ ((l & 7) << 4);
    int abase = pxl * 128;

    // hoist all tap params (27 independent loads, one latency)
    float tdy[9], tdx[9], tm[9];
#pragma unroll
    for (int k = 0; k < 9; ++k) {
        tdy[k] = tap[k*NPIX + gpix];
        tdx[k] = tap[(9+k)*NPIX + gpix];
        tm[k]  = tap[(18+k)*NPIX + gpix];
    }

    const u32x4* wsrc = (const u32x4*)wtF;
    {   // stage tap 0 into buffer 0
        u32x4 s0 = wsrc[tid], s1 = wsrc[tid+256], s2 = wsrc[tid+512], s3 = wsrc[tid+768];
        wlds[tid] = s0; wlds[tid+256] = s1; wlds[tid+512] = s2; wlds[tid+768] = s3;
    }
    __syncthreads();

    f32x4 acc[8];
#pragma unroll
    for (int i = 0; i < 8; ++i) acc[i] = (f32x4){0.f, 0.f, 0.f, 0.f};

#pragma unroll
    for (int k = 0; k < 9; ++k) {
        // issue next tap's staging loads early (T14: latency hides under compute)
        u32x4 s0, s1, s2, s3;
        if (k < 8) {
            const u32x4* ws2 = wsrc + (k+1)*1024;
            s0 = ws2[tid]; s1 = ws2[tid+256]; s2 = ws2[tid+512]; s3 = ws2[tid+768];
        }

        // ---- bilinear sampling -> B fragments (bf16 gathers, f32 lerp)
        float dy = tdy[k], dx = tdx[k], m = tm[k];
        int ki = k / 3, kj = k - ki*3;
        float py  = dy + (float)(ho - 1 + ki);
        float pxf = dx + (float)(wo - 1 + kj);
        float y0f = floorf(py), x0f = floorf(pxf);
        float ly = py - y0f, lxf = pxf - x0f;
        int y0 = (int)y0f, x0 = (int)x0f;
        int y1 = y0 + 1,  x1 = x0 + 1;
        bool vy0 = (y0 >= 0) && (y0 < HH), vy1 = (y1 >= 0) && (y1 < HH);
        bool vx0 = (x0 >= 0) && (x0 < WW), vx1 = (x1 >= 0) && (x1 < WW);
        float hy = 1.f - ly, hx = 1.f - lxf;
        float w00 = (vy0 && vx0) ? hy*hx*m : 0.f;
        float w01 = (vy0 && vx1) ? hy*lxf*m : 0.f;
        float w10 = (vy1 && vx0) ? ly*hx*m : 0.f;
        float w11 = (vy1 && vx1) ? ly*lxf*m : 0.f;
        int yc0 = min(max(y0, 0), HH-1), yc1 = min(max(y1, 0), HH-1);
        int xc0 = min(max(x0, 0), WW-1), xc1 = min(max(x1, 0), WW-1);
        const u32x4* p00 = (const u32x4*)(xtb + ((b*HH + yc0)*WW + xc0)*32);
        const u32x4* p01 = (const u32x4*)(xtb + ((b*HH + yc0)*WW + xc1)*32);
        const u32x4* p10 = (const u32x4*)(xtb + ((b*HH + yc1)*WW + xc0)*32);
        const u32x4* p11 = (const u32x4*)(xtb + ((b*HH + yc1)*WW + xc1)*32);

        u32x4 g00 = p00[hi],   g01 = p01[hi],   g10 = p10[hi],   g11 = p11[hi];
        u32x4 h00 = p00[hi+4], h01 = p01[hi+4], h10 = p10[hi+4], h11 = p11[hi+4];
        bf16x8 bf0 = lerp8(g00, g01, g10, g11, w00, w01, w10, w11);
        bf16x8 bf1 = lerp8(h00, h01, h10, h11, w00, w01, w10, w11);

        // ---- MFMA from current buffer
        const char* wb = (const char*)wlds + (k & 1)*16384;
#pragma unroll
        for (int mi = 0; mi < 8; ++mi) {
            u32x4 a0 = *(const u32x4*)(wb + (abase + lo0 + mi*2048));
            u32x4 a1 = *(const u32x4*)(wb + (abase + lo1 + mi*2048));
            acc[mi] = __builtin_amdgcn_mfma_f32_16x16x32_bf16(
                          __builtin_bit_cast(bf16x8, a0), bf0, acc[mi], 0, 0, 0);
            acc[mi] = __builtin_amdgcn_mfma_f32_16x16x32_bf16(
                          __builtin_bit_cast(bf16x8, a1), bf1, acc[mi], 0, 0, 0);
        }

        // ---- write next buffer, single barrier per tap
        if (k < 8) {
            u32x4* nb = wlds + ((k+1) & 1)*1024;
            nb[tid] = s0; nb[tid+256] = s1; nb[tid+512] = s2; nb[tid+768] = s3;
        }
        __syncthreads();
    }

#pragma unroll
    for (int mi = 0; mi < 8; ++mi) {
#pragma unroll
        for (int r = 0; r < 4; ++r) {
            int o = mi*16 + hi*4 + r;     // C/D: col=lane&15(px), row=(lane>>4)*4+reg
            out[((b*CO + o)*HH + ho)*WW + wo] = acc[mi][r];
        }
    }
}

// ---------------------------------------------------------------------------
extern "C" void kernel_launch(void* const* d_in, const int* in_sizes, int n_in,
                              void* d_out, int out_size, void* d_ws, size_t ws_size,
                              hipStream_t stream) {
    const float* x  = (const float*)d_in[0];
    const float* ow = (const float*)d_in[1];
    const float* ob = (const float*)d_in[2];
    const float* wm = (const float*)d_in[3];
    float* outp = (float*)d_out;

    float* ws   = (float*)d_ws;
    unsigned int* xtb = (unsigned int*)(ws + XTB_OFF);
    float* tap  = ws + TAP_OFF;
    unsigned short* owb = (unsigned short*)(ws + OWB_OFF);
    unsigned short* wtF = (unsigned short*)(ws + WTF_OFF);

    k_transpose_x<<<1024, 256, 0, stream>>>(x, xtb);
    k_prep_w<<<360, 256, 0, stream>>>(ow, wm, owb, wtF);
    k_offconv<<<1024, 256, 0, stream>>>(xtb, owb, ob, tap);
    k_main<<<1024, 256, 0, stream>>>(xtb, tap, wtF, outp);
}

// Round 8
// 71.927 us; speedup vs baseline: 4.4345x; 1.0611x over previous
//
#include <hip/hip_runtime.h>
#include <math.h>

// Problem constants
#define BB   4
#define CIN  64
#define HH   64
#define WW   256
#define CO   128
#define NPIX (BB*HH*WW)       // 65536

typedef float  f32x4 __attribute__((ext_vector_type(4)));
typedef unsigned int u32x4 __attribute__((ext_vector_type(4)));
typedef _Float16 f16x8 __attribute__((ext_vector_type(8)));
typedef _Float16 f16x2 __attribute__((ext_vector_type(2)));

// Workspace layout (float/u32 slots). Total ~15.7 MB.
#define XTB_OFF  0
#define XTB_SZ   (NPIX*32)            // 2097152 u32: f16 x as [b][y][x][c], 2ch/u32
#define TAP_OFF  (XTB_OFF + XTB_SZ)
#define TAP_SZ   (27*NPIX)            // planes: dy[9], dx[9], mask[9] (f32)
#define OWB_OFF  (TAP_OFF + TAP_SZ)
#define OWB_SZ   9216                 // 18432 f16: offconv A-fragments [18][2][64][8]
#define WTF_OFF  (OWB_OFF + OWB_SZ)   // ushort[9][8192] f16 A-frag, XOR-swizzled

// ---------------------------------------------------------------------------
// K0x: x [B][C][H][W] f32 -> xtb [B][H][W][C] f16 (packed 2ch/u32, linear order)
__global__ __launch_bounds__(256) void k_transpose_x(const float* __restrict__ x,
                                                     unsigned int* __restrict__ xtb) {
    __shared__ float t[64][65];
    int bx = blockIdx.x;           // 1024 blocks: (b, y, xtile)
    int x0 = (bx & 3) * 64;
    int y  = (bx >> 2) & 63;
    int b  = bx >> 8;
    int tid = threadIdx.x;
    int lx = tid & 63, gy = tid >> 6;
#pragma unroll
    for (int i = 0; i < 16; ++i) {
        int c = i * 4 + gy;
        t[c][lx] = x[((b*CIN + c)*HH + y)*WW + x0 + lx];
    }
    __syncthreads();
    int px = tid & 63, cg = tid >> 6;      // 16 channels per cg
    u32x4 r0, r1;
#pragma unroll
    for (int j = 0; j < 4; ++j) {
        f16x2 p, q;
        p[0] = (_Float16)t[cg*16 + 2*j][px];
        p[1] = (_Float16)t[cg*16 + 2*j + 1][px];
        q[0] = (_Float16)t[cg*16 + 8 + 2*j][px];
        q[1] = (_Float16)t[cg*16 + 8 + 2*j + 1][px];
        r0[j] = __builtin_bit_cast(unsigned int, p);
        r1[j] = __builtin_bit_cast(unsigned int, q);
    }
    u32x4* dst = (u32x4*)(xtb + (((b*HH + y)*WW) + x0 + px)*32 + cg*8);
    dst[0] = r0; dst[1] = r1;
}

// ---------------------------------------------------------------------------
// K0w: weight prep (f16).
//  owb: offconv weights as f16 A-fragments. elem e = ((kk*2+mi)*64+l)*8+j holds
//       W[oc=mi*16+(l&15)][k=kk*32+(l>>4)*8+j], k=t*64+c, 0 for oc>=27.
//  wtF [k][ (o*64+c) ^ ((o&7)<<3) ]: f16, A-fragment rows pre-swizzled
__global__ __launch_bounds__(256) void k_prep_w(const float* __restrict__ ow,
                                                const float* __restrict__ wm,
                                                unsigned short* __restrict__ owb,
                                                unsigned short* __restrict__ wtF) {
    const int n1 = 18432;
    const int n2 = 9*CO*CIN;
    for (int i = blockIdx.x*blockDim.x + threadIdx.x;
         i < n1 + n2; i += gridDim.x*blockDim.x) {
        if (i < n1) {
            int j = i & 7, l = (i >> 3) & 63, mi = (i >> 9) & 1, kk = i >> 10;
            int oc = mi*16 + (l & 15);
            int k  = kk*32 + (l >> 4)*8 + j;
            int t = k >> 6, c = k & 63;
            float v = (oc < 27) ? ow[(oc*CIN + c)*9 + t] : 0.f;
            owb[i] = __builtin_bit_cast(unsigned short, (_Float16)v);
        } else {
            int j = i - n1;
            int k = j / (CO*CIN);
            int r = j % (CO*CIN);      // r = o*64 + c
            int o = r / CIN, c = r % CIN;
            float v = wm[(o*CIN + c)*9 + k];
            wtF[k*8192 + (r ^ ((o & 7) << 3))] =
                __builtin_bit_cast(unsigned short, (_Float16)v);
        }
    }
}

// ---------------------------------------------------------------------------
// K1: offset conv via f16 MFMA. 1024 blocks x 4 waves; wave = 32(oc) x 16(px).
__global__ __launch_bounds__(256) void k_offconv(const unsigned int* __restrict__ xtb,
                                                 const unsigned short* __restrict__ owb,
                                                 const float* __restrict__ ob,
                                                 float* __restrict__ tap) {
    __shared__ u32x4 awl[2304];        // 36864 B
    int bx = blockIdx.x;               // 1024: (b, ho, wtile)
    int wtile = bx & 3, ho = (bx >> 2) & 63, b = bx >> 8;
    int tid = threadIdx.x;
    {
        const u32x4* asrc = (const u32x4*)owb;
#pragma unroll
        for (int i = 0; i < 9; ++i) awl[tid + i*256] = asrc[tid + i*256];
    }
    __syncthreads();
    int w = tid >> 6, l = tid & 63;
    int pxl = l & 15, hi = l >> 4;
    int wo = wtile*64 + w*16 + pxl;

    f32x4 acc0 = (f32x4){0.f,0.f,0.f,0.f}, acc1 = (f32x4){0.f,0.f,0.f,0.f};
#pragma unroll
    for (int kk = 0; kk < 18; ++kk) {
        const int t = kk >> 1;
        const int ki = t / 3, kj = t % 3;
        int y  = ho + ki - 1;
        int xx = wo + kj - 1;
        bool v = (y >= 0) && (y < HH) && (xx >= 0) && (xx < WW);
        int yc = min(max(y, 0), HH-1), xc = min(max(xx, 0), WW-1);
        const u32x4* p = (const u32x4*)(xtb + ((b*HH + yc)*WW + xc)*32);
        u32x4 bv = p[(kk & 1)*4 + hi];
        if (!v) bv = (u32x4){0u,0u,0u,0u};
        u32x4 a0 = awl[(kk*2+0)*64 + l];
        u32x4 a1 = awl[(kk*2+1)*64 + l];
        acc0 = __builtin_amdgcn_mfma_f32_16x16x32_f16(
                   __builtin_bit_cast(f16x8, a0), __builtin_bit_cast(f16x8, bv), acc0, 0, 0, 0);
        acc1 = __builtin_amdgcn_mfma_f32_16x16x32_f16(
                   __builtin_bit_cast(f16x8, a1), __builtin_bit_cast(f16x8, bv), acc1, 0, 0, 0);
    }

    int gpix = (b*HH + ho)*WW + wo;
#pragma unroll
    for (int r = 0; r < 4; ++r) {
        int oc0 = hi*4 + r;                       // 0..15: dy/dx planes
        float v0 = acc0[r] + ob[oc0];
        int plane0 = (oc0 & 1)*9 + (oc0 >> 1);
        tap[plane0*NPIX + gpix] = v0;
        int oc1 = 16 + hi*4 + r;                  // 16..31
        if (oc1 < 27) {
            float v1 = acc1[r] + ob[oc1];
            float vv; int plane1;
            if (oc1 < 18) { plane1 = (oc1 & 1)*9 + (oc1 >> 1); vv = v1; }
            else { plane1 = oc1; vv = 1.f / (1.f + __expf(-v1)); }
            tap[plane1*NPIX + gpix] = vv;
        }
    }
}

// ---------------------------------------------------------------------------
// packed-f16 bilinear lerp: r = a*w0 + b*w1 + c*w2 + d*w3 (v_pk_fma_f16)
__device__ inline f16x8 lerp8h(u32x4 a, u32x4 b, u32x4 c, u32x4 d,
                               f16x8 w0, f16x8 w1, f16x8 w2, f16x8 w3) {
    f16x8 av = __builtin_bit_cast(f16x8, a);
    f16x8 bv = __builtin_bit_cast(f16x8, b);
    f16x8 cv = __builtin_bit_cast(f16x8, c);
    f16x8 dv = __builtin_bit_cast(f16x8, d);
    return av*w0 + bv*w1 + cv*w2 + dv*w3;
}

__device__ inline f16x8 splat8(float s) {
    _Float16 h = (_Float16)s;
    return (f16x8){h, h, h, h, h, h, h, h};
}

// ---------------------------------------------------------------------------
// K2: fused deformable sampling + f16 MFMA GEMM.
// Wave = 128(o) x 16(px). Lane l: px=l&15, hi=l>>4; f16 gathers: 8 x 16B per tap.
// Weights: LDS double-buffer (2 x 16KB), ONE barrier per tap.
__global__ __launch_bounds__(256) void k_main(const unsigned int* __restrict__ xtb,
                                              const float* __restrict__ tap,
                                              const unsigned short* __restrict__ wtF,
                                              float* __restrict__ out) {
    __shared__ u32x4 wlds[2048];   // 32 KB: two 16KB buffers
    int bx = blockIdx.x;
    int wtile = bx & 3, ho = (bx >> 2) & 63, b = bx >> 8;
    int tid = threadIdx.x;
    int w = tid >> 6;
    int l = tid & 63;
    int pxl = l & 15, hi = l >> 4;
    int wo = wtile*64 + w*16 + pxl;
    int gpix = (b*HH + ho)*WW + wo;

    // A-fragment swizzled LDS byte offsets (within a 16KB buffer)
    int lo0 = (hi*16)      ^ ((l & 7) << 4);
    int lo1 = (64 + hi*16) ^ ((l & 7) << 4);
    int abase = pxl * 128;

    // hoist all tap params (27 independent loads, one latency)
    float tdy[9], tdx[9], tm[9];
#pragma unroll
    for (int k = 0; k < 9; ++k) {
        tdy[k] = tap[k*NPIX + gpix];
        tdx[k] = tap[(9+k)*NPIX + gpix];
        tm[k]  = tap[(18+k)*NPIX + gpix];
    }

    const u32x4* wsrc = (const u32x4*)wtF;
    {   // stage tap 0 into buffer 0
        u32x4 s0 = wsrc[tid], s1 = wsrc[tid+256], s2 = wsrc[tid+512], s3 = wsrc[tid+768];
        wlds[tid] = s0; wlds[tid+256] = s1; wlds[tid+512] = s2; wlds[tid+768] = s3;
    }
    __syncthreads();

    f32x4 acc[8];
#pragma unroll
    for (int i = 0; i < 8; ++i) acc[i] = (f32x4){0.f, 0.f, 0.f, 0.f};

#pragma unroll
    for (int k = 0; k < 9; ++k) {
        // issue next tap's staging loads early (T14: latency hides under compute)
        u32x4 s0, s1, s2, s3;
        if (k < 8) {
            const u32x4* ws2 = wsrc + (k+1)*1024;
            s0 = ws2[tid]; s1 = ws2[tid+256]; s2 = ws2[tid+512]; s3 = ws2[tid+768];
        }

        // ---- bilinear sampling -> B fragments (f16 gathers, packed-f16 lerp)
        float dy = tdy[k], dx = tdx[k], m = tm[k];
        int ki = k / 3, kj = k - ki*3;
        float py  = dy + (float)(ho - 1 + ki);
        float pxf = dx + (float)(wo - 1 + kj);
        float y0f = floorf(py), x0f = floorf(pxf);
        float ly = py - y0f, lxf = pxf - x0f;
        int y0 = (int)y0f, x0 = (int)x0f;
        int y1 = y0 + 1,  x1 = x0 + 1;
        bool vy0 = (y0 >= 0) && (y0 < HH), vy1 = (y1 >= 0) && (y1 < HH);
        bool vx0 = (x0 >= 0) && (x0 < WW), vx1 = (x1 >= 0) && (x1 < WW);
        float hy = 1.f - ly, hx = 1.f - lxf;
        float w00 = (vy0 && vx0) ? hy*hx*m : 0.f;
        float w01 = (vy0 && vx1) ? hy*lxf*m : 0.f;
        float w10 = (vy1 && vx0) ? ly*hx*m : 0.f;
        float w11 = (vy1 && vx1) ? ly*lxf*m : 0.f;
        int yc0 = min(max(y0, 0), HH-1), yc1 = min(max(y1, 0), HH-1);
        int xc0 = min(max(x0, 0), WW-1), xc1 = min(max(x1, 0), WW-1);
        const u32x4* p00 = (const u32x4*)(xtb + ((b*HH + yc0)*WW + xc0)*32);
        const u32x4* p01 = (const u32x4*)(xtb + ((b*HH + yc0)*WW + xc1)*32);
        const u32x4* p10 = (const u32x4*)(xtb + ((b*HH + yc1)*WW + xc0)*32);
        const u32x4* p11 = (const u32x4*)(xtb + ((b*HH + yc1)*WW + xc1)*32);

        u32x4 g00 = p00[hi],   g01 = p01[hi],   g10 = p10[hi],   g11 = p11[hi];
        u32x4 h00 = p00[hi+4], h01 = p01[hi+4], h10 = p10[hi+4], h11 = p11[hi+4];
        f16x8 w0v = splat8(w00), w1v = splat8(w01), w2v = splat8(w10), w3v = splat8(w11);
        f16x8 bf0 = lerp8h(g00, g01, g10, g11, w0v, w1v, w2v, w3v);
        f16x8 bf1 = lerp8h(h00, h01, h10, h11, w0v, w1v, w2v, w3v);

        // ---- MFMA from current buffer
        const char* wb = (const char*)wlds + (k & 1)*16384;
#pragma unroll
        for (int mi = 0; mi < 8; ++mi) {
            u32x4 a0 = *(const u32x4*)(wb + (abase + lo0 + mi*2048));
            u32x4 a1 = *(const u32x4*)(wb + (abase + lo1 + mi*2048));
            acc[mi] = __builtin_amdgcn_mfma_f32_16x16x32_f16(
                          __builtin_bit_cast(f16x8, a0), bf0, acc[mi], 0, 0, 0);
            acc[mi] = __builtin_amdgcn_mfma_f32_16x16x32_f16(
                          __builtin_bit_cast(f16x8, a1), bf1, acc[mi], 0, 0, 0);
        }

        // ---- write next buffer, single barrier per tap
        if (k < 8) {
            u32x4* nb = wlds + ((k+1) & 1)*1024;
            nb[tid] = s0; nb[tid+256] = s1; nb[tid+512] = s2; nb[tid+768] = s3;
        }
        __syncthreads();
    }

#pragma unroll
    for (int mi = 0; mi < 8; ++mi) {
#pragma unroll
        for (int r = 0; r < 4; ++r) {
            int o = mi*16 + hi*4 + r;     // C/D: col=lane&15(px), row=(lane>>4)*4+reg
            out[((b*CO + o)*HH + ho)*WW + wo] = acc[mi][r];
        }
    }
}

// ---------------------------------------------------------------------------
extern "C" void kernel_launch(void* const* d_in, const int* in_sizes, int n_in,
                              void* d_out, int out_size, void* d_ws, size_t ws_size,
                              hipStream_t stream) {
    const float* x  = (const float*)d_in[0];
    const float* ow = (const float*)d_in[1];
    const float* ob = (const float*)d_in[2];
    const float* wm = (const float*)d_in[3];
    float* outp = (float*)d_out;

    float* ws   = (float*)d_ws;
    unsigned int* xtb = (unsigned int*)(ws + XTB_OFF);
    float* tap  = ws + TAP_OFF;
    unsigned short* owb = (unsigned short*)(ws + OWB_OFF);
    unsigned short* wtF = (unsigned short*)(ws + WTF_OFF);

    k_transpose_x<<<1024, 256, 0, stream>>>(x, xtb);
    k_prep_w<<<360, 256, 0, stream>>>(ow, wm, owb, wtF);
    k_offconv<<<1024, 256, 0, stream>>>(xtb, owb, ob, tap);
    k_main<<<1024, 256, 0, stream>>>(xtb, tap, wtF, outp);
}

// Round 9
// 66.184 us; speedup vs baseline: 4.8193x; 1.0868x over previous
//
#include <hip/hip_runtime.h>
#include <math.h>

// Problem constants
#define BB   4
#define CIN  64
#define HH   64
#define WW   256
#define CO   128
#define NPIX (BB*HH*WW)       // 65536

typedef float  f32x4 __attribute__((ext_vector_type(4)));
typedef unsigned int u32x4 __attribute__((ext_vector_type(4)));
typedef _Float16 f16x8 __attribute__((ext_vector_type(8)));
typedef _Float16 f16x2 __attribute__((ext_vector_type(2)));

// Workspace layout (float/u32 slots). Total ~15.7 MB.
#define XTB_OFF  0
#define XTB_SZ   (NPIX*32)            // 2097152 u32: f16 x as [b][y][x][c], 2ch/u32
#define TAP_OFF  (XTB_OFF + XTB_SZ)
#define TAP_SZ   (27*NPIX)            // planes: dy[9], dx[9], mask[9] (f32)
#define OWB_OFF  (TAP_OFF + TAP_SZ)
#define OWB_SZ   9216                 // 18432 f16: offconv A-fragments [18][2][64][8]
#define WTF_OFF  (OWB_OFF + OWB_SZ)   // ushort[9][8192] f16 A-frag, XOR-swizzled

// XCD-aware block swizzle: 1024 = 8 XCDs x 128. Same mapping for transpose/
// offconv/main so producer and consumer of a row share an XCD L2.
__device__ inline int xcd_swz(int bid) { return (bid & 7) * 128 + (bid >> 3); }

// ---------------------------------------------------------------------------
// K0x: x [B][C][H][W] f32 -> xtb [B][H][W][C] f16 (packed 2ch/u32, linear order)
__global__ __launch_bounds__(256) void k_transpose_x(const float* __restrict__ x,
                                                     unsigned int* __restrict__ xtb) {
    __shared__ float t[64][65];
    int bx = xcd_swz(blockIdx.x);  // 1024 blocks: (b, y, xtile)
    int x0 = (bx & 3) * 64;
    int y  = (bx >> 2) & 63;
    int b  = bx >> 8;
    int tid = threadIdx.x;
    int lx = tid & 63, gy = tid >> 6;
#pragma unroll
    for (int i = 0; i < 16; ++i) {
        int c = i * 4 + gy;
        t[c][lx] = x[((b*CIN + c)*HH + y)*WW + x0 + lx];
    }
    __syncthreads();
    int px = tid & 63, cg = tid >> 6;      // 16 channels per cg
    u32x4 r0, r1;
#pragma unroll
    for (int j = 0; j < 4; ++j) {
        f16x2 p, q;
        p[0] = (_Float16)t[cg*16 + 2*j][px];
        p[1] = (_Float16)t[cg*16 + 2*j + 1][px];
        q[0] = (_Float16)t[cg*16 + 8 + 2*j][px];
        q[1] = (_Float16)t[cg*16 + 8 + 2*j + 1][px];
        r0[j] = __builtin_bit_cast(unsigned int, p);
        r1[j] = __builtin_bit_cast(unsigned int, q);
    }
    u32x4* dst = (u32x4*)(xtb + (((b*HH + y)*WW) + x0 + px)*32 + cg*8);
    dst[0] = r0; dst[1] = r1;
}

// ---------------------------------------------------------------------------
// K0w: weight prep (f16).
//  owb: offconv weights as f16 A-fragments. elem e = ((kk*2+mi)*64+l)*8+j holds
//       W[oc=mi*16+(l&15)][k=kk*32+(l>>4)*8+j], k=t*64+c, 0 for oc>=27.
//  wtF [k][ (o*64+c) ^ ((o&7)<<3) ]: f16, A-fragment rows pre-swizzled
__global__ __launch_bounds__(256) void k_prep_w(const float* __restrict__ ow,
                                                const float* __restrict__ wm,
                                                unsigned short* __restrict__ owb,
                                                unsigned short* __restrict__ wtF) {
    const int n1 = 18432;
    const int n2 = 9*CO*CIN;
    for (int i = blockIdx.x*blockDim.x + threadIdx.x;
         i < n1 + n2; i += gridDim.x*blockDim.x) {
        if (i < n1) {
            int j = i & 7, l = (i >> 3) & 63, mi = (i >> 9) & 1, kk = i >> 10;
            int oc = mi*16 + (l & 15);
            int k  = kk*32 + (l >> 4)*8 + j;
            int t = k >> 6, c = k & 63;
            float v = (oc < 27) ? ow[(oc*CIN + c)*9 + t] : 0.f;
            owb[i] = __builtin_bit_cast(unsigned short, (_Float16)v);
        } else {
            int j = i - n1;
            int k = j / (CO*CIN);
            int r = j % (CO*CIN);      // r = o*64 + c
            int o = r / CIN, c = r % CIN;
            float v = wm[(o*CIN + c)*9 + k];
            wtF[k*8192 + (r ^ ((o & 7) << 3))] =
                __builtin_bit_cast(unsigned short, (_Float16)v);
        }
    }
}

// ---------------------------------------------------------------------------
// K1: offset conv via f16 MFMA. 1024 blocks x 4 waves; wave = 32(oc) x 16(px).
__global__ __launch_bounds__(256) void k_offconv(const unsigned int* __restrict__ xtb,
                                                 const unsigned short* __restrict__ owb,
                                                 const float* __restrict__ ob,
                                                 float* __restrict__ tap) {
    __shared__ u32x4 awl[2304];        // 36864 B
    int bx = xcd_swz(blockIdx.x);      // 1024: (b, ho, wtile)
    int wtile = bx & 3, ho = (bx >> 2) & 63, b = bx >> 8;
    int tid = threadIdx.x;
    {
        const u32x4* asrc = (const u32x4*)owb;
#pragma unroll
        for (int i = 0; i < 9; ++i) awl[tid + i*256] = asrc[tid + i*256];
    }
    __syncthreads();
    int w = tid >> 6, l = tid & 63;
    int pxl = l & 15, hi = l >> 4;
    int wo = wtile*64 + w*16 + pxl;

    f32x4 acc0 = (f32x4){0.f,0.f,0.f,0.f}, acc1 = (f32x4){0.f,0.f,0.f,0.f};
#pragma unroll
    for (int kk = 0; kk < 18; ++kk) {
        const int t = kk >> 1;
        const int ki = t / 3, kj = t % 3;
        int y  = ho + ki - 1;
        int xx = wo + kj - 1;
        bool v = (y >= 0) && (y < HH) && (xx >= 0) && (xx < WW);
        int yc = min(max(y, 0), HH-1), xc = min(max(xx, 0), WW-1);
        const u32x4* p = (const u32x4*)(xtb + ((b*HH + yc)*WW + xc)*32);
        u32x4 bv = p[(kk & 1)*4 + hi];
        if (!v) bv = (u32x4){0u,0u,0u,0u};
        u32x4 a0 = awl[(kk*2+0)*64 + l];
        u32x4 a1 = awl[(kk*2+1)*64 + l];
        acc0 = __builtin_amdgcn_mfma_f32_16x16x32_f16(
                   __builtin_bit_cast(f16x8, a0), __builtin_bit_cast(f16x8, bv), acc0, 0, 0, 0);
        acc1 = __builtin_amdgcn_mfma_f32_16x16x32_f16(
                   __builtin_bit_cast(f16x8, a1), __builtin_bit_cast(f16x8, bv), acc1, 0, 0, 0);
    }

    int gpix = (b*HH + ho)*WW + wo;
#pragma unroll
    for (int r = 0; r < 4; ++r) {
        int oc0 = hi*4 + r;                       // 0..15: dy/dx planes
        float v0 = acc0[r] + ob[oc0];
        int plane0 = (oc0 & 1)*9 + (oc0 >> 1);
        tap[plane0*NPIX + gpix] = v0;
        int oc1 = 16 + hi*4 + r;                  // 16..31
        if (oc1 < 27) {
            float v1 = acc1[r] + ob[oc1];
            float vv; int plane1;
            if (oc1 < 18) { plane1 = (oc1 & 1)*9 + (oc1 >> 1); vv = v1; }
            else { plane1 = oc1; vv = 1.f / (1.f + __expf(-v1)); }
            tap[plane1*NPIX + gpix] = vv;
        }
    }
}

// ---------------------------------------------------------------------------
// packed-f16 bilinear lerp: r = a*w0 + b*w1 + c*w2 + d*w3 (v_pk_fma_f16)
__device__ inline f16x8 lerp8h(u32x4 a, u32x4 b, u32x4 c, u32x4 d,
                               f16x8 w0, f16x8 w1, f16x8 w2, f16x8 w3) {
    f16x8 av = __builtin_bit_cast(f16x8, a);
    f16x8 bv = __builtin_bit_cast(f16x8, b);
    f16x8 cv = __builtin_bit_cast(f16x8, c);
    f16x8 dv = __builtin_bit_cast(f16x8, d);
    return av*w0 + bv*w1 + cv*w2 + dv*w3;
}

__device__ inline f16x8 splat8(float s) {
    _Float16 h = (_Float16)s;
    return (f16x8){h, h, h, h, h, h, h, h};
}

// ---------------------------------------------------------------------------
// K2: fused deformable sampling + f16 MFMA GEMM.
// Wave = 128(o) x 16(px). Lane l: px=l&15, hi=l>>4; f16 gathers: 8 x 16B per tap.
// 2-deep gather pipeline (tap k+1 issued before lerp of tap k); weight LDS
// double-buffer with lgkm-only barrier (no vmcnt drain -> pipeline survives).
__global__ __launch_bounds__(256) void k_main(const unsigned int* __restrict__ xtb,
                                              const float* __restrict__ tap,
                                              const unsigned short* __restrict__ wtF,
                                              float* __restrict__ out) {
    __shared__ u32x4 wlds[2048];   // 32 KB: two 16KB buffers
    int bx = xcd_swz(blockIdx.x);
    int wtile = bx & 3, ho = (bx >> 2) & 63, b = bx >> 8;
    int tid = threadIdx.x;
    int w = tid >> 6;
    int l = tid & 63;
    int pxl = l & 15, hi = l >> 4;
    int wo = wtile*64 + w*16 + pxl;
    int gpix = (b*HH + ho)*WW + wo;

    // A-fragment swizzled LDS byte offsets (within a 16KB buffer)
    int lo0 = (hi*16)      ^ ((l & 7) << 4);
    int lo1 = (64 + hi*16) ^ ((l & 7) << 4);
    int abase = pxl * 128;

    // hoist all tap params (27 independent loads, one latency)
    float tdy[9], tdx[9], tm[9];
#pragma unroll
    for (int k = 0; k < 9; ++k) {
        tdy[k] = tap[k*NPIX + gpix];
        tdx[k] = tap[(9+k)*NPIX + gpix];
        tm[k]  = tap[(18+k)*NPIX + gpix];
    }

    // compute addresses + issue the 8 gathers + lerp weights for tap k
    auto issue_tap = [&](int k, u32x4* G, float* W) {
        float dy = tdy[k], dx = tdx[k], m = tm[k];
        int ki = k / 3, kj = k - ki*3;
        float py  = dy + (float)(ho - 1 + ki);
        float pxf = dx + (float)(wo - 1 + kj);
        float y0f = floorf(py), x0f = floorf(pxf);
        float ly = py - y0f, lxf = pxf - x0f;
        int y0 = (int)y0f, x0 = (int)x0f;
        int y1 = y0 + 1,  x1 = x0 + 1;
        bool vy0 = (y0 >= 0) && (y0 < HH), vy1 = (y1 >= 0) && (y1 < HH);
        bool vx0 = (x0 >= 0) && (x0 < WW), vx1 = (x1 >= 0) && (x1 < WW);
        float hy = 1.f - ly, hx = 1.f - lxf;
        W[0] = (vy0 && vx0) ? hy*hx*m : 0.f;
        W[1] = (vy0 && vx1) ? hy*lxf*m : 0.f;
        W[2] = (vy1 && vx0) ? ly*hx*m : 0.f;
        W[3] = (vy1 && vx1) ? ly*lxf*m : 0.f;
        int yc0 = min(max(y0, 0), HH-1), yc1 = min(max(y1, 0), HH-1);
        int xc0 = min(max(x0, 0), WW-1), xc1 = min(max(x1, 0), WW-1);
        const u32x4* p00 = (const u32x4*)(xtb + ((b*HH + yc0)*WW + xc0)*32);
        const u32x4* p01 = (const u32x4*)(xtb + ((b*HH + yc0)*WW + xc1)*32);
        const u32x4* p10 = (const u32x4*)(xtb + ((b*HH + yc1)*WW + xc0)*32);
        const u32x4* p11 = (const u32x4*)(xtb + ((b*HH + yc1)*WW + xc1)*32);
        G[0] = p00[hi];   G[1] = p01[hi];   G[2] = p10[hi];   G[3] = p11[hi];
        G[4] = p00[hi+4]; G[5] = p01[hi+4]; G[6] = p10[hi+4]; G[7] = p11[hi+4];
    };

    const u32x4* wsrc = (const u32x4*)wtF;
    {   // stage tap 0 weights into buffer 0
        u32x4 s0 = wsrc[tid], s1 = wsrc[tid+256], s2 = wsrc[tid+512], s3 = wsrc[tid+768];
        wlds[tid] = s0; wlds[tid+256] = s1; wlds[tid+512] = s2; wlds[tid+768] = s3;
    }
    __syncthreads();

    f32x4 acc[8];
#pragma unroll
    for (int i = 0; i < 8; ++i) acc[i] = (f32x4){0.f, 0.f, 0.f, 0.f};

    u32x4 GA[8], GB[8];
    float WA[4], WB[4];
    issue_tap(0, GA, WA);

#pragma unroll
    for (int k = 0; k < 9; ++k) {
        u32x4 *G, *Gn; float *W, *Wn;
        if (k & 1) { G = GB; W = WB; Gn = GA; Wn = WA; }
        else       { G = GA; W = WA; Gn = GB; Wn = WB; }

        // issue next tap's weight-staging loads + gathers (latency hides under
        // this tap's lerp+MFMA)
        u32x4 s0, s1, s2, s3;
        if (k < 8) {
            const u32x4* ws2 = wsrc + (k+1)*1024;
            s0 = ws2[tid]; s1 = ws2[tid+256]; s2 = ws2[tid+512]; s3 = ws2[tid+768];
            issue_tap(k+1, Gn, Wn);
        }

        // ---- lerp tap k -> B fragments (packed f16 math)
        f16x8 w0v = splat8(W[0]), w1v = splat8(W[1]), w2v = splat8(W[2]), w3v = splat8(W[3]);
        f16x8 bf0 = lerp8h(G[0], G[1], G[2], G[3], w0v, w1v, w2v, w3v);
        f16x8 bf1 = lerp8h(G[4], G[5], G[6], G[7], w0v, w1v, w2v, w3v);

        // ---- MFMA from current buffer
        const char* wb = (const char*)wlds + (k & 1)*16384;
#pragma unroll
        for (int mi = 0; mi < 8; ++mi) {
            u32x4 a0 = *(const u32x4*)(wb + (abase + lo0 + mi*2048));
            u32x4 a1 = *(const u32x4*)(wb + (abase + lo1 + mi*2048));
            acc[mi] = __builtin_amdgcn_mfma_f32_16x16x32_f16(
                          __builtin_bit_cast(f16x8, a0), bf0, acc[mi], 0, 0, 0);
            acc[mi] = __builtin_amdgcn_mfma_f32_16x16x32_f16(
                          __builtin_bit_cast(f16x8, a1), bf1, acc[mi], 0, 0, 0);
        }

        // ---- write next buffer; lgkm-only barrier (keep gathers in flight)
        if (k < 8) {
            u32x4* nb = wlds + ((k+1) & 1)*1024;
            nb[tid] = s0; nb[tid+256] = s1; nb[tid+512] = s2; nb[tid+768] = s3;
            asm volatile("s_waitcnt lgkmcnt(0)\n\ts_barrier" ::: "memory");
        }
    }

#pragma unroll
    for (int mi = 0; mi < 8; ++mi) {
#pragma unroll
        for (int r = 0; r < 4; ++r) {
            int o = mi*16 + hi*4 + r;     // C/D: col=lane&15(px), row=(lane>>4)*4+reg
            out[((b*CO + o)*HH + ho)*WW + wo] = acc[mi][r];
        }
    }
}

// ---------------------------------------------------------------------------
extern "C" void kernel_launch(void* const* d_in, const int* in_sizes, int n_in,
                              void* d_out, int out_size, void* d_ws, size_t ws_size,
                              hipStream_t stream) {
    const float* x  = (const float*)d_in[0];
    const float* ow = (const float*)d_in[1];
    const float* ob = (const float*)d_in[2];
    const float* wm = (const float*)d_in[3];
    float* outp = (float*)d_out;

    float* ws   = (float*)d_ws;
    unsigned int* xtb = (unsigned int*)(ws + XTB_OFF);
    float* tap  = ws + TAP_OFF;
    unsigned short* owb = (unsigned short*)(ws + OWB_OFF);
    unsigned short* wtF = (unsigned short*)(ws + WTF_OFF);

    k_transpose_x<<<1024, 256, 0, stream>>>(x, xtb);
    k_prep_w<<<360, 256, 0, stream>>>(ow, wm, owb, wtF);
    k_offconv<<<1024, 256, 0, stream>>>(xtb, owb, ob, tap);
    k_main<<<1024, 256, 0, stream>>>(xtb, tap, wtF, outp);
}